// Round 1
// baseline (187.330 us; speedup 1.0000x reference)
//
#include <hip/hip_runtime.h>
#include <hip/hip_bf16.h>
#include <math.h>

#define N_NODES 50000
#define N_EDGES 200000
#define N_TASK  10000
#define VOCAB   1000
#define D       64
#define H       4
#define HC      256   // H*C

// ---------------------------------------------------------------------------
// K1: vocab tables (q/k/v/xr per vocab id) + task mask
//   blocks [0,125): 8 vocab rows each, 256 threads = one output column each
//   blocks [125,165): scatter mask[task_idx[i]] = 1
// ---------------------------------------------------------------------------
__global__ __launch_bounds__(256) void k_tables_mask(
    const float* __restrict__ emb,
    const float* __restrict__ Wq, const float* __restrict__ bq,
    const float* __restrict__ Wk, const float* __restrict__ bk,
    const float* __restrict__ Wv, const float* __restrict__ bv,
    const float* __restrict__ Wskip, const float* __restrict__ bskip,
    const int* __restrict__ task,
    float* __restrict__ qtab, float* __restrict__ ktab,
    float* __restrict__ vtab, float* __restrict__ xrtab,
    int* __restrict__ mask) {
  int b = blockIdx.x;
  int tid = threadIdx.x;
  if (b >= 125) {
    int i = (b - 125) * 256 + tid;
    if (i < N_TASK) mask[task[i]] = 1;
    return;
  }
  __shared__ float hs[8 * 64];
  int v0 = b * 8;
  hs[tid]       = emb[v0 * 64 + tid];
  hs[tid + 256] = emb[v0 * 64 + 256 + tid];
  __syncthreads();

  float aq[8], ak[8], av[8];
#pragma unroll
  for (int r = 0; r < 8; r++) { aq[r] = 0.f; ak[r] = 0.f; av[r] = 0.f; }
  for (int d = 0; d < 64; d++) {
    float wq = Wq[d * 256 + tid];
    float wk = Wk[d * 256 + tid];
    float wv = Wv[d * 256 + tid];
#pragma unroll
    for (int r = 0; r < 8; r++) {
      float h = hs[r * 64 + d];
      aq[r] += h * wq; ak[r] += h * wk; av[r] += h * wv;
    }
  }
#pragma unroll
  for (int r = 0; r < 8; r++) {
    qtab[(v0 + r) * 256 + tid] = aq[r] + bq[tid];
    ktab[(v0 + r) * 256 + tid] = ak[r] + bk[tid];
    vtab[(v0 + r) * 256 + tid] = av[r] + bv[tid];
  }
  if (tid < 64) {
    float as[8];
#pragma unroll
    for (int r = 0; r < 8; r++) as[r] = 0.f;
    for (int d = 0; d < 64; d++) {
      float w = Wskip[d * 64 + tid];
#pragma unroll
      for (int r = 0; r < 8; r++) as[r] += hs[r * 64 + d] * w;
    }
#pragma unroll
    for (int r = 0; r < 8; r++) xrtab[(v0 + r) * 64 + tid] = as[r] + bskip[tid];
  }
}

// ---------------------------------------------------------------------------
// K2: compact edges whose dst is in the task set
// ---------------------------------------------------------------------------
__global__ __launch_bounds__(256) void k_compact(
    const int* __restrict__ ei, const int* __restrict__ mask,
    int* __restrict__ cnt, int* __restrict__ elist) {
  int e = blockIdx.x * 256 + threadIdx.x;
  if (e >= N_EDGES) return;
  int dst = ei[N_EDGES + e];
  if (mask[dst]) {
    int p = atomicAdd(cnt, 1);
    elist[p] = e;
  }
}

// ---------------------------------------------------------------------------
// K3: per masked edge: alpha[h] = dot64(q[dst],k[src])/8; e = exp(alpha)
//     store e, atomicAdd denom[dst,h]. One wave per edge; lane = 4 floats.
// ---------------------------------------------------------------------------
__global__ __launch_bounds__(256) void k_alpha(
    const int* __restrict__ ei, const int* __restrict__ x,
    const float* __restrict__ qtab, const float* __restrict__ ktab,
    const int* __restrict__ elist, const int* __restrict__ cnt,
    float* __restrict__ ealpha, float* __restrict__ denom) {
  int n = cnt[0];
  int wave   = (blockIdx.x * blockDim.x + threadIdx.x) >> 6;
  int lane   = threadIdx.x & 63;
  int stride = (gridDim.x * blockDim.x) >> 6;
  for (int w = wave; w < n; w += stride) {
    int e = elist[w];
    int src = ei[e], dst = ei[N_EDGES + e];
    int xs = x[src], xd = x[dst];
    const float4* qr = (const float4*)(qtab + (size_t)xd * HC);
    const float4* kr = (const float4*)(ktab + (size_t)xs * HC);
    float4 q4 = qr[lane], k4 = kr[lane];
    float p = q4.x * k4.x + q4.y * k4.y + q4.z * k4.z + q4.w * k4.w;
    p += __shfl_xor(p, 1);
    p += __shfl_xor(p, 2);
    p += __shfl_xor(p, 4);
    p += __shfl_xor(p, 8);
    if ((lane & 15) == 0) {
      int h = lane >> 4;
      float ev = expf(p * 0.125f);   // scale = 1/sqrt(64)
      ealpha[(size_t)e * 4 + h] = ev;
      atomicAdd(&denom[(size_t)dst * 4 + h], ev);
    }
  }
}

// ---------------------------------------------------------------------------
// K4: per masked edge: out_mean[dst,d] += 0.25 * sum_h a[e,h]*v[src,h,d]
//     One wave per edge, lane = dim d. 64 atomics/edge.
// ---------------------------------------------------------------------------
__global__ __launch_bounds__(256) void k_agg(
    const int* __restrict__ ei, const int* __restrict__ x,
    const float* __restrict__ vtab,
    const int* __restrict__ elist, const int* __restrict__ cnt,
    const float* __restrict__ ealpha, const float* __restrict__ denom,
    float* __restrict__ omean) {
  int n = cnt[0];
  int wave   = (blockIdx.x * blockDim.x + threadIdx.x) >> 6;
  int lane   = threadIdx.x & 63;
  int stride = (gridDim.x * blockDim.x) >> 6;
  for (int w = wave; w < n; w += stride) {
    int e = elist[w];
    int src = ei[e], dst = ei[N_EDGES + e];
    int xs = x[src];
    const float* vr = vtab + (size_t)xs * HC;
    float a0 = ealpha[(size_t)e * 4 + 0] / denom[(size_t)dst * 4 + 0];
    float a1 = ealpha[(size_t)e * 4 + 1] / denom[(size_t)dst * 4 + 1];
    float a2 = ealpha[(size_t)e * 4 + 2] / denom[(size_t)dst * 4 + 2];
    float a3 = ealpha[(size_t)e * 4 + 3] / denom[(size_t)dst * 4 + 3];
    float acc = a0 * vr[lane] + a1 * vr[64 + lane] + a2 * vr[128 + lane]
              + a3 * vr[192 + lane];
    atomicAdd(&omean[(size_t)dst * 64 + lane], 0.25f * acc);
  }
}

// ---------------------------------------------------------------------------
// K5: per masked node: beta-gate. One wave per node, lane = dim d.
//   beta = sigmoid(dot(out,Wb0+Wb2) + dot(xr,Wb1-Wb2))
//   hnew = beta*xr + (1-beta)*out
// ---------------------------------------------------------------------------
__global__ __launch_bounds__(256) void k_epi(
    const int* __restrict__ x, const int* __restrict__ mask,
    const float* __restrict__ omean, const float* __restrict__ xrtab,
    const float* __restrict__ Wbeta, float* __restrict__ hnew) {
  int nidx = (blockIdx.x * blockDim.x + threadIdx.x) >> 6;
  int lane = threadIdx.x & 63;
  if (nidx >= N_NODES) return;
  if (!mask[nidx]) return;
  float om = omean[(size_t)nidx * 64 + lane];
  float xr = xrtab[(size_t)x[nidx] * 64 + lane];
  float wb0 = Wbeta[lane], wb1 = Wbeta[64 + lane], wb2 = Wbeta[128 + lane];
  float p = om * (wb0 + wb2) + xr * (wb1 - wb2);
  p += __shfl_xor(p, 1);
  p += __shfl_xor(p, 2);
  p += __shfl_xor(p, 4);
  p += __shfl_xor(p, 8);
  p += __shfl_xor(p, 16);
  p += __shfl_xor(p, 32);
  float beta = 1.f / (1.f + expf(-p));
  hnew[(size_t)nidx * 64 + lane] = beta * xr + (1.f - beta) * om;
}

// ---------------------------------------------------------------------------
// K6: task head: risk = sigmoid(relu(hs@W1+b1)@W2+b2). One thread per task.
// ---------------------------------------------------------------------------
__global__ __launch_bounds__(256) void k_task(
    const int* __restrict__ task, const float* __restrict__ hnew,
    const float* __restrict__ W1, const float* __restrict__ b1,
    const float* __restrict__ W2, const float* __restrict__ b2,
    float* __restrict__ out) {
  int t = blockIdx.x * 256 + threadIdx.x;
  if (t >= N_TASK) return;
  int n = task[t];
  const float* hv = hnew + (size_t)n * 64;
  float acc[32];
#pragma unroll
  for (int j = 0; j < 32; j++) acc[j] = b1[j];
  for (int d = 0; d < 64; d++) {
    float hd = hv[d];
#pragma unroll
    for (int j = 0; j < 32; j++) acc[j] += hd * W1[d * 32 + j];
  }
  float z = b2[0];
#pragma unroll
  for (int j = 0; j < 32; j++) z += fmaxf(acc[j], 0.f) * W2[j];
  out[t] = 1.f / (1.f + expf(-z));
}

// ---------------------------------------------------------------------------
extern "C" void kernel_launch(void* const* d_in, const int* in_sizes, int n_in,
                              void* d_out, int out_size, void* d_ws, size_t ws_size,
                              hipStream_t stream) {
  const int*   x     = (const int*)d_in[0];
  const int*   ei    = (const int*)d_in[1];
  const int*   task  = (const int*)d_in[2];
  const float* emb   = (const float*)d_in[3];
  const float* Wq    = (const float*)d_in[4];
  const float* bq    = (const float*)d_in[5];
  const float* Wk    = (const float*)d_in[6];
  const float* bk    = (const float*)d_in[7];
  const float* Wv    = (const float*)d_in[8];
  const float* bv    = (const float*)d_in[9];
  const float* Wskip = (const float*)d_in[10];
  const float* bskip = (const float*)d_in[11];
  const float* Wbeta = (const float*)d_in[12];
  const float* W1    = (const float*)d_in[13];
  const float* b1    = (const float*)d_in[14];
  const float* W2    = (const float*)d_in[15];
  const float* b2    = (const float*)d_in[16];
  float* out = (float*)d_out;

  char* ws = (char*)d_ws;
  size_t off = 0;
  auto alloc = [&](size_t bytes) {
    size_t o = off;
    off += (bytes + 255) & ~(size_t)255;
    return o;
  };
  // zeroed region first
  int*   cnt   = (int*)(ws + alloc(sizeof(int)));
  int*   mask  = (int*)(ws + alloc(sizeof(int) * N_NODES));
  float* denom = (float*)(ws + alloc(sizeof(float) * N_NODES * 4));
  float* omean = (float*)(ws + alloc(sizeof(float) * (size_t)N_NODES * 64));
  size_t zero_bytes = off;
  // non-zeroed scratch
  float* qtab  = (float*)(ws + alloc(sizeof(float) * VOCAB * HC));
  float* ktab  = (float*)(ws + alloc(sizeof(float) * VOCAB * HC));
  float* vtab  = (float*)(ws + alloc(sizeof(float) * VOCAB * HC));
  float* xrtab = (float*)(ws + alloc(sizeof(float) * VOCAB * 64));
  int*   elist = (int*)(ws + alloc(sizeof(int) * N_EDGES));
  float* ealph = (float*)(ws + alloc(sizeof(float) * (size_t)N_EDGES * 4));
  float* hnew  = (float*)(ws + alloc(sizeof(float) * (size_t)N_NODES * 64));
  (void)ws_size; (void)n_in; (void)in_sizes; (void)out_size;

  hipMemsetAsync(d_ws, 0, zero_bytes, stream);

  k_tables_mask<<<125 + (N_TASK + 255) / 256, 256, 0, stream>>>(
      emb, Wq, bq, Wk, bk, Wv, bv, Wskip, bskip, task,
      qtab, ktab, vtab, xrtab, mask);

  k_compact<<<(N_EDGES + 255) / 256, 256, 0, stream>>>(ei, mask, cnt, elist);

  // 12500 blocks * 4 waves = 50000 waves; grid-stride over cnt (~36.5K edges)
  k_alpha<<<12500, 256, 0, stream>>>(ei, x, qtab, ktab, elist, cnt, ealph, denom);

  k_agg<<<12500, 256, 0, stream>>>(ei, x, vtab, elist, cnt, ealph, denom, omean);

  k_epi<<<(N_NODES + 3) / 4, 256, 0, stream>>>(x, mask, omean, xrtab, Wbeta, hnew);

  k_task<<<(N_TASK + 255) / 256, 256, 0, stream>>>(task, hnew, W1, b1, W2, b2, out);
}

// Round 2
// 141.499 us; speedup vs baseline: 1.3239x; 1.3239x over previous
//
#include <hip/hip_runtime.h>
#include <hip/hip_bf16.h>
#include <math.h>

#define N_NODES 50000
#define N_EDGES 200000
#define N_TASK  10000
#define VOCAB   1000
#define D       64
#define H       4
#define HC      256   // H*C

// ---------------------------------------------------------------------------
// K1: vocab tables (q/k/v/xr per vocab id) + task mask scatter
//   blocks [0,125): 8 vocab rows each, 256 threads = one output column each
//   blocks [125,165): scatter mask[task_idx[i]] = 1
// ---------------------------------------------------------------------------
__global__ __launch_bounds__(256) void k_tables_mask(
    const float* __restrict__ emb,
    const float* __restrict__ Wq, const float* __restrict__ bq,
    const float* __restrict__ Wk, const float* __restrict__ bk,
    const float* __restrict__ Wv, const float* __restrict__ bv,
    const float* __restrict__ Wskip, const float* __restrict__ bskip,
    const int* __restrict__ task,
    float* __restrict__ qtab, float* __restrict__ ktab,
    float* __restrict__ vtab, float* __restrict__ xrtab,
    int* __restrict__ mask) {
  int b = blockIdx.x;
  int tid = threadIdx.x;
  if (b >= 125) {
    int i = (b - 125) * 256 + tid;
    if (i < N_TASK) mask[task[i]] = 1;
    return;
  }
  __shared__ float hs[8 * 64];
  int v0 = b * 8;
  hs[tid]       = emb[v0 * 64 + tid];
  hs[tid + 256] = emb[v0 * 64 + 256 + tid];
  __syncthreads();

  float aq[8], ak[8], av[8];
#pragma unroll
  for (int r = 0; r < 8; r++) { aq[r] = 0.f; ak[r] = 0.f; av[r] = 0.f; }
  for (int d = 0; d < 64; d++) {
    float wq = Wq[d * 256 + tid];
    float wk = Wk[d * 256 + tid];
    float wv = Wv[d * 256 + tid];
#pragma unroll
    for (int r = 0; r < 8; r++) {
      float h = hs[r * 64 + d];
      aq[r] += h * wq; ak[r] += h * wk; av[r] += h * wv;
    }
  }
#pragma unroll
  for (int r = 0; r < 8; r++) {
    qtab[(v0 + r) * 256 + tid] = aq[r] + bq[tid];
    ktab[(v0 + r) * 256 + tid] = ak[r] + bk[tid];
    vtab[(v0 + r) * 256 + tid] = av[r] + bv[tid];
  }
  if (tid < 64) {
    float as[8];
#pragma unroll
    for (int r = 0; r < 8; r++) as[r] = 0.f;
    for (int d = 0; d < 64; d++) {
      float w = Wskip[d * 64 + tid];
#pragma unroll
      for (int r = 0; r < 8; r++) as[r] += hs[r * 64 + d] * w;
    }
#pragma unroll
    for (int r = 0; r < 8; r++) xrtab[(v0 + r) * 64 + tid] = as[r] + bskip[tid];
  }
}

// ---------------------------------------------------------------------------
// K2: degree count for masked-dst edges
// ---------------------------------------------------------------------------
__global__ __launch_bounds__(256) void k_deg(
    const int* __restrict__ ei, const int* __restrict__ mask,
    int* __restrict__ deg) {
  int e = blockIdx.x * 256 + threadIdx.x;
  if (e >= N_EDGES) return;
  int dst = ei[N_EDGES + e];
  if (mask[dst]) atomicAdd(&deg[dst], 1);
}

// ---------------------------------------------------------------------------
// K3: bump-allocate CSR slots per masked node (wave-level prefix scan,
//     one atomic per wave) + build compact masked-node list
// ---------------------------------------------------------------------------
__global__ __launch_bounds__(256) void k_alloc(
    const int* __restrict__ mask, const int* __restrict__ deg,
    int* __restrict__ start, int* __restrict__ cursor,
    int* __restrict__ edgecnt, int* __restrict__ nodecnt,
    int* __restrict__ nlist) {
  int n = blockIdx.x * 256 + threadIdx.x;
  int lane = threadIdx.x & 63;
  bool m = (n < N_NODES) && (mask[n] != 0);
  int d = m ? deg[n] : 0;
  // inclusive wave scan of d
  int incl = d;
#pragma unroll
  for (int o = 1; o < 64; o <<= 1) {
    int t = __shfl_up(incl, o);
    if (lane >= o) incl += t;
  }
  int wavetot = __shfl(incl, 63);
  int base = 0;
  if (lane == 63 && wavetot > 0) base = atomicAdd(edgecnt, wavetot);
  base = __shfl(base, 63);
  int st = base + incl - d;
  // masked-node list append
  unsigned long long b = __ballot(m);
  int npre = __popcll(b & ((1ull << lane) - 1ull));
  int ntot = __popcll(b);
  int nbase = 0;
  if (lane == 0 && ntot > 0) nbase = atomicAdd(nodecnt, ntot);
  nbase = __shfl(nbase, 0);
  if (m) {
    start[n]  = st;
    cursor[n] = st;
    nlist[nbase + npre] = n;
  }
}

// ---------------------------------------------------------------------------
// K4: fill CSR — store the SRC VOCAB ID directly (all the gather needs)
// ---------------------------------------------------------------------------
__global__ __launch_bounds__(256) void k_fill(
    const int* __restrict__ ei, const int* __restrict__ x,
    const int* __restrict__ mask, int* __restrict__ cursor,
    int* __restrict__ ecsr) {
  int e = blockIdx.x * 256 + threadIdx.x;
  if (e >= N_EDGES) return;
  int dst = ei[N_EDGES + e];
  if (mask[dst]) {
    int p = atomicAdd(&cursor[dst], 1);
    ecsr[p] = x[ei[e]];
  }
}

// ---------------------------------------------------------------------------
// K5: per masked node, ONE wave, single pass:
//   softmax (unnormalized accumulate, divide at end) + head-mean + beta gate.
//   Lane layout: head h = lane>>4, float4 chunk j = lane&15 (dims 4j..4j+3).
// ---------------------------------------------------------------------------
__global__ __launch_bounds__(256) void k_node(
    const int* __restrict__ nlist, const int* __restrict__ nodecnt,
    const int* __restrict__ x, const int* __restrict__ start,
    const int* __restrict__ deg, const float* __restrict__ qtab,
    const float* __restrict__ ktab, const float* __restrict__ vtab,
    const float* __restrict__ xrtab, const float* __restrict__ Wbeta,
    const int* __restrict__ ecsr, float* __restrict__ hnew) {
  int w    = (blockIdx.x * blockDim.x + threadIdx.x) >> 6;
  int lane = threadIdx.x & 63;
  int nw   = (gridDim.x * blockDim.x) >> 6;
  int cnt  = nodecnt[0];
  for (; w < cnt; w += nw) {
    int node = nlist[w];
    int xd = x[node];
    float4 q4 = ((const float4*)(qtab + (size_t)xd * HC))[lane];
    int s = start[node];
    int dc = deg[node];
    float denom = 0.f;
    float4 num = make_float4(0.f, 0.f, 0.f, 0.f);
    for (int i = 0; i < dc; i++) {
      int xs = ecsr[s + i];
      const float4* kr = (const float4*)(ktab + (size_t)xs * HC);
      const float4* vr = (const float4*)(vtab + (size_t)xs * HC);
      float4 k4 = kr[lane];
      float p = q4.x * k4.x + q4.y * k4.y + q4.z * k4.z + q4.w * k4.w;
      p += __shfl_xor(p, 1);
      p += __shfl_xor(p, 2);
      p += __shfl_xor(p, 4);
      p += __shfl_xor(p, 8);
      float ev = __expf(p * 0.125f);   // scale = 1/sqrt(64); softmax shift-free
      float4 v4 = vr[lane];
      num.x += ev * v4.x; num.y += ev * v4.y;
      num.z += ev * v4.z; num.w += ev * v4.w;
      denom += ev;
    }
    float inv = (dc > 0) ? (1.f / denom) : 0.f;
    float4 om = make_float4(num.x * inv, num.y * inv, num.z * inv, num.w * inv);
    // mean over heads: lanes xor 16/32 hold same dims, different heads
    om.x += __shfl_xor(om.x, 16); om.y += __shfl_xor(om.y, 16);
    om.z += __shfl_xor(om.z, 16); om.w += __shfl_xor(om.w, 16);
    om.x += __shfl_xor(om.x, 32); om.y += __shfl_xor(om.y, 32);
    om.z += __shfl_xor(om.z, 32); om.w += __shfl_xor(om.w, 32);
    om.x *= 0.25f; om.y *= 0.25f; om.z *= 0.25f; om.w *= 0.25f;
    // beta gate: p = om·(wb0+wb2) + xr·(wb1-wb2), dot over 64 dims
    int j = lane & 15;
    float4 xr  = ((const float4*)(xrtab + (size_t)xd * D))[j];
    float4 wb0 = ((const float4*)(Wbeta))[j];
    float4 wb1 = ((const float4*)(Wbeta + 64))[j];
    float4 wb2 = ((const float4*)(Wbeta + 128))[j];
    float p = om.x * (wb0.x + wb2.x) + om.y * (wb0.y + wb2.y)
            + om.z * (wb0.z + wb2.z) + om.w * (wb0.w + wb2.w)
            + xr.x * (wb1.x - wb2.x) + xr.y * (wb1.y - wb2.y)
            + xr.z * (wb1.z - wb2.z) + xr.w * (wb1.w - wb2.w);
    p += __shfl_xor(p, 1);
    p += __shfl_xor(p, 2);
    p += __shfl_xor(p, 4);
    p += __shfl_xor(p, 8);
    float beta = 1.f / (1.f + __expf(-p));
    if (lane < 16) {
      float4 hv = make_float4(beta * xr.x + (1.f - beta) * om.x,
                              beta * xr.y + (1.f - beta) * om.y,
                              beta * xr.z + (1.f - beta) * om.z,
                              beta * xr.w + (1.f - beta) * om.w);
      ((float4*)(hnew + (size_t)node * D))[j] = hv;
    }
  }
}

// ---------------------------------------------------------------------------
// K6: task head — 4 lanes per task, each handles 8 of 32 hidden units
// ---------------------------------------------------------------------------
__global__ __launch_bounds__(256) void k_task(
    const int* __restrict__ task, const float* __restrict__ hnew,
    const float* __restrict__ W1, const float* __restrict__ b1,
    const float* __restrict__ W2, const float* __restrict__ b2,
    float* __restrict__ out) {
  int g = blockIdx.x * 256 + threadIdx.x;
  int t = g >> 2;
  int q = g & 3;            // quarter: hidden units 8q..8q+7
  if (t >= N_TASK) return;
  int n = task[t];
  const float* hv = hnew + (size_t)n * 64;
  float acc[8];
#pragma unroll
  for (int j = 0; j < 8; j++) acc[j] = b1[q * 8 + j];
  for (int d = 0; d < 64; d++) {
    float hd = hv[d];
#pragma unroll
    for (int j = 0; j < 8; j++) acc[j] += hd * W1[d * 32 + q * 8 + j];
  }
  float z = 0.f;
#pragma unroll
  for (int j = 0; j < 8; j++) z += fmaxf(acc[j], 0.f) * W2[q * 8 + j];
  z += __shfl_xor(z, 1);
  z += __shfl_xor(z, 2);
  if (q == 0) out[t] = 1.f / (1.f + __expf(-(z + b2[0])));
}

// ---------------------------------------------------------------------------
extern "C" void kernel_launch(void* const* d_in, const int* in_sizes, int n_in,
                              void* d_out, int out_size, void* d_ws, size_t ws_size,
                              hipStream_t stream) {
  const int*   x     = (const int*)d_in[0];
  const int*   ei    = (const int*)d_in[1];
  const int*   task  = (const int*)d_in[2];
  const float* emb   = (const float*)d_in[3];
  const float* Wq    = (const float*)d_in[4];
  const float* bq    = (const float*)d_in[5];
  const float* Wk    = (const float*)d_in[6];
  const float* bk    = (const float*)d_in[7];
  const float* Wv    = (const float*)d_in[8];
  const float* bv    = (const float*)d_in[9];
  const float* Wskip = (const float*)d_in[10];
  const float* bskip = (const float*)d_in[11];
  const float* Wbeta = (const float*)d_in[12];
  const float* W1    = (const float*)d_in[13];
  const float* b1    = (const float*)d_in[14];
  const float* W2    = (const float*)d_in[15];
  const float* b2    = (const float*)d_in[16];
  float* out = (float*)d_out;

  char* ws = (char*)d_ws;
  size_t off = 0;
  auto alloc = [&](size_t bytes) {
    size_t o = off;
    off += (bytes + 255) & ~(size_t)255;
    return o;
  };
  // ---- zeroed region (must come first) ----
  int* edgecnt = (int*)(ws + alloc(sizeof(int)));
  int* nodecnt = (int*)(ws + alloc(sizeof(int)));
  int* mask    = (int*)(ws + alloc(sizeof(int) * N_NODES));
  int* deg     = (int*)(ws + alloc(sizeof(int) * N_NODES));
  size_t zero_bytes = off;
  // ---- uninitialized scratch ----
  int*   start  = (int*)(ws + alloc(sizeof(int) * N_NODES));
  int*   cursor = (int*)(ws + alloc(sizeof(int) * N_NODES));
  int*   nlist  = (int*)(ws + alloc(sizeof(int) * N_NODES));
  int*   ecsr   = (int*)(ws + alloc(sizeof(int) * N_EDGES));
  float* qtab   = (float*)(ws + alloc(sizeof(float) * VOCAB * HC));
  float* ktab   = (float*)(ws + alloc(sizeof(float) * VOCAB * HC));
  float* vtab   = (float*)(ws + alloc(sizeof(float) * VOCAB * HC));
  float* xrtab  = (float*)(ws + alloc(sizeof(float) * VOCAB * 64));
  float* hnew   = (float*)(ws + alloc(sizeof(float) * (size_t)N_NODES * 64));
  (void)ws_size; (void)n_in; (void)in_sizes; (void)out_size;

  hipMemsetAsync(d_ws, 0, zero_bytes, stream);

  k_tables_mask<<<125 + (N_TASK + 255) / 256, 256, 0, stream>>>(
      emb, Wq, bq, Wk, bk, Wv, bv, Wskip, bskip, task,
      qtab, ktab, vtab, xrtab, mask);

  k_deg<<<(N_EDGES + 255) / 256, 256, 0, stream>>>(ei, mask, deg);

  k_alloc<<<(N_NODES + 255) / 256, 256, 0, stream>>>(
      mask, deg, start, cursor, edgecnt, nodecnt, nlist);

  k_fill<<<(N_EDGES + 255) / 256, 256, 0, stream>>>(ei, x, mask, cursor, ecsr);

  // ~9K masked nodes expected; 2400 blocks * 4 waves = 9600 waves grid-stride
  k_node<<<2400, 256, 0, stream>>>(nlist, nodecnt, x, start, deg,
                                   qtab, ktab, vtab, xrtab, Wbeta, ecsr, hnew);

  k_task<<<(N_TASK * 4 + 255) / 256, 256, 0, stream>>>(
      task, hnew, W1, b1, W2, b2, out);
}